// Round 10
// baseline (255.581 us; speedup 1.0000x reference)
//
#include <hip/hip_runtime.h>
#include <hip/hip_bf16.h>

typedef __bf16 bf16x8 __attribute__((ext_vector_type(8)));
typedef float  f32x4  __attribute__((ext_vector_type(4)));

static constexpr int E    = 1965;   // J*D + J*3
static constexpr int KF   = 1920;   // J*D
static constexpr int NJ   = 15;
static constexpr int NCLS = 68;
static constexpr int NPAD = 80;     // 5 tiles of 16
static constexpr int NT   = 5;
static constexpr int NS   = 60;     // k-steps of 32
static constexpr int CH   = 30;     // chunks of 2 k-steps (64 fp32 cols)
static constexpr int NBUF = 3;      // chunk buffers: compute c, c+1/c+2 in flight

// ws layout:
//   pnf: [NT][NS][64][8] __bf16  = 307200 B
//   pa : [NPAD][45] float        = 14400 B
static constexpr size_t PNF_BYTES = (size_t)NT * NS * 64 * 8 * 2;

// ---------------- kernel 1: normalize W -> bf16 fragments + angle extract ----
__global__ __launch_bounds__(256) void prep_kernel(const float* __restrict__ W,
                                                   __bf16* __restrict__ pnf,
                                                   float* __restrict__ pa) {
    const int n = blockIdx.x;      // 0..79
    const int t = threadIdx.x;     // 0..255
    float v[8];
    float ss = 0.f;
    if (n < NCLS && t < 240) {
        const float* src = W + (size_t)n * E + 8 * t;
        #pragma unroll
        for (int i = 0; i < 8; ++i) { v[i] = src[i]; ss += v[i] * v[i]; }
    } else {
        #pragma unroll
        for (int i = 0; i < 8; ++i) v[i] = 0.f;
    }
    #pragma unroll
    for (int off = 32; off >= 1; off >>= 1) ss += __shfl_xor(ss, off);
    __shared__ float rbuf[4];
    if ((t & 63) == 0) rbuf[t >> 6] = ss;
    __syncthreads();
    const float total = rbuf[0] + rbuf[1] + rbuf[2] + rbuf[3];
    const float rnorm = 1.f / fmaxf(sqrtf(total), 1e-12f);

    if (t < 240) {
        bf16x8 o;
        #pragma unroll
        for (int i = 0; i < 8; ++i) o[i] = (__bf16)(v[i] * rnorm);
        const int s = t >> 2, g = t & 3;
        const int lane = (n & 15) + 16 * g;
        const size_t off = (((size_t)(n >> 4) * NS + s) * 64 + lane) * 8;
        *(bf16x8*)(pnf + off) = o;
    }
    if (t < 45) {
        pa[n * 45 + t] = (n < NCLS) ? W[(size_t)n * E + KF + t] : 0.f;
    }
}

// ---------------- kernel 2: all-DMA, depth-2 counted-vmcnt GEMM + epilogue ----
// Chunk = 2 k-steps (64 fp32 cols). Per chunk: 4 A-DMA (issued by waves 0-3)
// + 2 B-DMA per wave. Per-wave queue is DMA-only; steady-state wait is
// vmcnt(3|2) = "my chunk-c ops landed, chunk-c+1 in flight" + 1 barrier/chunk.
// A LDS layout IS the fragment layout ([s][h][lane] 16B units) -> all loop
// ds_reads are base+lane*16 b128: conflict-free by construction.
__global__ __launch_bounds__(320) void cos_kernel(const float* __restrict__ emb,
                                                  const __bf16* __restrict__ pnf,
                                                  const float* __restrict__ pa,
                                                  float* __restrict__ out) {
    __shared__ f32x4  Abuf[NBUF][2][2][64];    // [buf][s][h][lane] : 12,288 B
    __shared__ __bf16 Bbuf[NBUF][NT][2][512];  // [buf][w][s][l*8]  : 30,720 B
    __shared__ float  xa[16][48];              //                     3,072 B

    const int tid = threadIdx.x;
    const int m0  = blockIdx.x * 16;
    const int w   = tid >> 6;    // wave = N-tile 0..4 (wave-uniform)
    const int l   = tid & 63;
    const int lr  = l & 15;      // A row / B col within tile
    const int lg  = l >> 4;      // k-group

    // ---- xa staging (drained before first barrier) ----
    for (int idx = tid; idx < 16 * 45; idx += 320) {
        const int r = idx / 45, c = idx - r * 45;
        xa[r][c] = emb[(size_t)(m0 + r) * E + KF + c];
    }
    asm volatile("s_waitcnt lgkmcnt(0)" ::: "memory");

    // ---- DMA sources ----
    // A instr (s=w>>1, h=w&1): lane l -> row l&15, cols 64c + 32s + 8*(l>>4) + 4h
    const float* srcA = emb + (size_t)(m0 + lr) * E + 8 * lg + 32 * (w >> 1) + 4 * (w & 1);
    // B: lane l -> fragment unit l of step (2c+s) of tile w
    const __bf16* srcB = pnf + ((size_t)w * NS * 64 + l) * 8;

    #define ISSUE(c)                                                                     \
        {                                                                                \
            if (w < 4)                                                                   \
                __builtin_amdgcn_global_load_lds(                                        \
                    (const __attribute__((address_space(1))) void*)(srcA + 64 * (c)),    \
                    (__attribute__((address_space(3))) void*)&Abuf[(c) % NBUF][w >> 1][w & 1][0], \
                    16, 0, 0);                                                           \
            _Pragma("unroll")                                                            \
            for (int s_ = 0; s_ < 2; ++s_)                                               \
                __builtin_amdgcn_global_load_lds(                                        \
                    (const __attribute__((address_space(1))) void*)(srcB + (2 * (c) + s_) * 512), \
                    (__attribute__((address_space(3))) void*)&Bbuf[(c) % NBUF][w][s_][0],         \
                    16, 0, 0);                                                           \
        }

    f32x4 acc[NJ];
    #pragma unroll
    for (int j = 0; j < NJ; ++j) acc[j] = f32x4{0.f, 0.f, 0.f, 0.f};
    float ssq = 0.f;

    ISSUE(0);
    ISSUE(1);

    #pragma unroll
    for (int c = 0; c < CH; ++c) {
        // wait: my chunk-c DMA landed (chunk c+1 stays in flight)
        if (c == CH - 1)  { asm volatile("s_waitcnt vmcnt(0)" ::: "memory"); }
        else if (w < 4)   { asm volatile("s_waitcnt vmcnt(3)" ::: "memory"); }
        else              { asm volatile("s_waitcnt vmcnt(2)" ::: "memory"); }
        __builtin_amdgcn_sched_barrier(0);
        __builtin_amdgcn_s_barrier();          // everyone's chunk-c landed; slot free
        __builtin_amdgcn_sched_barrier(0);
        if (c + 2 < CH) ISSUE(c + 2);
        __builtin_amdgcn_sched_barrier(0);

        #pragma unroll
        for (int s = 0; s < 2; ++s) {
            const f32x4 alo = Abuf[c % NBUF][s][0][l];
            const f32x4 ahi = Abuf[c % NBUF][s][1][l];
            const bf16x8 b  = *(const bf16x8*)&Bbuf[c % NBUF][w][s][l * 8];
            bf16x8 af;
            #pragma unroll
            for (int q = 0; q < 4; ++q) {
                ssq += alo[q] * alo[q] + ahi[q] * ahi[q];
                af[q]     = (__bf16)alo[q];
                af[4 + q] = (__bf16)ahi[q];
            }
            const int gk = 2 * c + s;
            acc[gk >> 2] = __builtin_amdgcn_mfma_f32_16x16x32_bf16(af, b, acc[gk >> 2], 0, 0, 0);
        }
    }
    #undef ISSUE

    // ---- row norms: lanes {lr, lr+16, lr+32, lr+48} hold row-lr partials ----
    ssq += __shfl_xor(ssq, 16);
    ssq += __shfl_xor(ssq, 32);

    const int r0  = lg * 4;      // C/D: row = (lane>>4)*4 + reg, col = lane&15
    const int col = w * 16 + lr;

    float rn[4];
    #pragma unroll
    for (int r = 0; r < 4; ++r)
        rn[r] = 240.f / fmaxf(sqrtf(__shfl(ssq, r0 + r)), 1e-12f);   // 16*15/norm

    // ---- angle softmax epilogue (pa is 14.4 KB, cache-hot) ----
    const float* pav = pa + col * 45;
    float num[4] = {0.f, 0.f, 0.f, 0.f};
    float den[4] = {0.f, 0.f, 0.f, 0.f};
    #pragma unroll
    for (int j = 0; j < NJ; ++j) {
        const float p0a = pav[3 * j + 0];
        const float p1a = pav[3 * j + 1];
        const float p2a = pav[3 * j + 2];
        #pragma unroll
        for (int r = 0; r < 4; ++r) {
            const float d0 = xa[r0 + r][3 * j + 0] - p0a;
            const float d1 = xa[r0 + r][3 * j + 1] - p1a;
            const float d2 = xa[r0 + r][3 * j + 2] - p2a;
            const float dist = sqrtf(d0 * d0 + d1 * d1 + d2 * d2);
            const float e = __expf(dist * 0.005f);   // exponents in [0, ~0.05]
            den[r] += e;
            num[r] += e * acc[j][r];
        }
    }

    if (col < NCLS) {
        #pragma unroll
        for (int r = 0; r < 4; ++r)
            out[(size_t)(m0 + r0 + r) * NCLS + col] = rn[r] * num[r] / den[r];
    }
}

extern "C" void kernel_launch(void* const* d_in, const int* in_sizes, int n_in,
                              void* d_out, int out_size, void* d_ws, size_t ws_size,
                              hipStream_t stream) {
    const float* emb = (const float*)d_in[0];
    const float* W   = (const float*)d_in[1];
    float* out = (float*)d_out;
    __bf16* pnf = (__bf16*)d_ws;
    float*  pa  = (float*)((char*)d_ws + PNF_BYTES);
    const int B = in_sizes[0] / E;           // 16384

    prep_kernel<<<NPAD, 256, 0, stream>>>(W, pnf, pa);
    cos_kernel<<<B / 16, 320, 0, stream>>>(emb, pnf, pa, out);
}

// Round 11
// 102.785 us; speedup vs baseline: 2.4866x; 2.4866x over previous
//
#include <hip/hip_runtime.h>
#include <hip/hip_bf16.h>

typedef __bf16 bf16x8 __attribute__((ext_vector_type(8)));
typedef float  f32x4  __attribute__((ext_vector_type(4)));

static constexpr int E    = 1965;   // J*D + J*3
static constexpr int KF   = 1920;   // J*D
static constexpr int NJ   = 15;
static constexpr int NCLS = 68;
static constexpr int NPAD = 80;     // 5 tiles of 16
static constexpr int NT   = 5;
static constexpr int NS   = 60;     // k-steps of 32
static constexpr int NCH  = 4;      // K-chunks
static constexpr int SPC  = 15;     // k-steps per chunk (480 fp32 cols)

// ws layout:
//   pnf: [NT][NS][64][8] __bf16  = 307200 B
//   pa : [NPAD][45] float        = 14400 B
static constexpr size_t PNF_BYTES = (size_t)NT * NS * 64 * 8 * 2;

// ---------------- kernel 1: normalize W -> bf16 fragments + angle extract ----
__global__ __launch_bounds__(256) void prep_kernel(const float* __restrict__ W,
                                                   __bf16* __restrict__ pnf,
                                                   float* __restrict__ pa) {
    const int n = blockIdx.x;      // 0..79
    const int t = threadIdx.x;     // 0..255
    float v[8];
    float ss = 0.f;
    if (n < NCLS && t < 240) {
        const float* src = W + (size_t)n * E + 8 * t;
        #pragma unroll
        for (int i = 0; i < 8; ++i) { v[i] = src[i]; ss += v[i] * v[i]; }
    } else {
        #pragma unroll
        for (int i = 0; i < 8; ++i) v[i] = 0.f;
    }
    #pragma unroll
    for (int off = 32; off >= 1; off >>= 1) ss += __shfl_xor(ss, off);
    __shared__ float rbuf[4];
    if ((t & 63) == 0) rbuf[t >> 6] = ss;
    __syncthreads();
    const float total = rbuf[0] + rbuf[1] + rbuf[2] + rbuf[3];
    const float rnorm = 1.f / fmaxf(sqrtf(total), 1e-12f);

    if (t < 240) {
        bf16x8 o;
        #pragma unroll
        for (int i = 0; i < 8; ++i) o[i] = (__bf16)(v[i] * rnorm);
        const int s = t >> 2, g = t & 3;
        const int lane = (n & 15) + 16 * g;
        const size_t off = (((size_t)(n >> 4) * NS + s) * 64 + lane) * 8;
        *(bf16x8*)(pnf + off) = o;
    }
    if (t < 45) {
        pa[n * 45 + t] = (n < NCLS) ? W[(size_t)n * E + KF + t] : 0.f;
    }
}

// ---------------- kernel 2: all-DMA A staging + rotating-joint accumulator ----
// Chunk = 15 k-steps (480 fp32 cols, 30 KB). Per chunk each wave issues 6
// global_load_lds (1 KB each); counted vmcnt(6) keeps the next chunk in
// flight across the barrier. acc is ONE rotating f32x4 per joint (folded into
// num/den with angle-softmax weights immediately) -> ~13 live regs instead of
// 60, so the compiler has room to pipeline B-loads. Inner stream is asm-free.
__global__ __launch_bounds__(320) void cos_kernel(const float* __restrict__ emb,
                                                  const __bf16* __restrict__ pnf,
                                                  const float* __restrict__ pa,
                                                  float* __restrict__ out) {
    __shared__ f32x4  Abuf[2][SPC][2][64];   // [buf][s][h][lane] : 61,440 B
    __shared__ __bf16 pal[NPAD][52];         //                      8,320 B
    __shared__ float  xa[16][48];            //                      3,072 B

    const int tid = threadIdx.x;
    const int m0  = blockIdx.x * 16;
    const int wv  = tid >> 6;    // wave = N-tile 0..4 (wave-uniform)
    const int l   = tid & 63;
    const int lr  = l & 15;      // A row / B col within tile
    const int lg  = l >> 4;      // k-group

    // ---- angle staging (drained by lgkmcnt(0) before prologue barrier) ----
    for (int idx = tid; idx < 16 * 45; idx += 320) {
        const int r = idx / 45, c = idx - r * 45;
        xa[r][c] = emb[(size_t)(m0 + r) * E + KF + c];
    }
    for (int idx = tid; idx < NPAD * 45; idx += 320) {
        const int n = idx / 45, c = idx - n * 45;
        pal[n][c] = (__bf16)pa[idx];
    }

    // ---- DMA decode: wave wv, instr i -> flat=6wv+i, s=flat>>1, h=flat&1;
    //      lane l -> row l&15, cols 480c + 32s + 8*(l>>4) + 4h  (R9-verified)
    const float*  srcA = emb + (size_t)(m0 + lr) * E + 8 * lg;
    const __bf16* srcB = pnf + ((size_t)wv * NS * 64 + l) * 8;

    #define ISSUE(c)                                                                     \
        {                                                                                \
            _Pragma("unroll")                                                            \
            for (int i_ = 0; i_ < 6; ++i_) {                                             \
                const int fl_ = 6 * wv + i_, s_ = fl_ >> 1, h_ = fl_ & 1;                \
                __builtin_amdgcn_global_load_lds(                                        \
                    (const __attribute__((address_space(1))) void*)(srcA + 480 * (c) + 32 * s_ + 4 * h_), \
                    (__attribute__((address_space(3))) void*)&Abuf[(c) & 1][s_][h_][0],  \
                    16, 0, 0);                                                           \
            }                                                                            \
        }

    const int r0  = lg * 4;      // C/D: row = (lane>>4)*4 + reg, col = lane&15
    const int col = wv * 16 + lr;

    float num[4] = {0.f, 0.f, 0.f, 0.f};
    float den[4] = {0.f, 0.f, 0.f, 0.f};
    float ssq = 0.f;
    f32x4 aj = f32x4{0.f, 0.f, 0.f, 0.f};

    // prologue: chunks 0,1 in flight; wait chunk 0 + angle ds_writes
    ISSUE(0);
    ISSUE(1);
    asm volatile("s_waitcnt vmcnt(6) lgkmcnt(0)" ::: "memory");
    __builtin_amdgcn_s_barrier();
    __builtin_amdgcn_sched_barrier(0);

    #pragma unroll
    for (int c = 0; c < NCH; ++c) {
        if (c > 0) {
            __builtin_amdgcn_sched_barrier(0);
            __builtin_amdgcn_s_barrier();        // buf[(c+1)&1] readers done
            __builtin_amdgcn_sched_barrier(0);
            if (c + 1 < NCH) {
                ISSUE(c + 1);
                __builtin_amdgcn_sched_barrier(0);
                asm volatile("s_waitcnt vmcnt(6)" ::: "memory");   // chunk c landed
            } else {
                asm volatile("s_waitcnt vmcnt(0)" ::: "memory");
            }
            __builtin_amdgcn_sched_barrier(0);
            __builtin_amdgcn_s_barrier();        // all waves' chunk c landed
            __builtin_amdgcn_sched_barrier(0);
        }

        #pragma unroll
        for (int sl = 0; sl < SPC; ++sl) {
            const int gs = SPC * c + sl;         // global k-step, 0..59 (static)
            const f32x4 alo = Abuf[c & 1][sl][0][l];
            const f32x4 ahi = Abuf[c & 1][sl][1][l];
            const bf16x8 b  = *(const bf16x8*)(srcB + (size_t)gs * 512);
            bf16x8 af;
            #pragma unroll
            for (int q = 0; q < 4; ++q) {
                ssq += alo[q] * alo[q] + ahi[q] * ahi[q];
                af[q]     = (__bf16)alo[q];
                af[4 + q] = (__bf16)ahi[q];
            }
            aj = __builtin_amdgcn_mfma_f32_16x16x32_bf16(af, b, aj, 0, 0, 0);

            if ((gs & 3) == 3) {                 // joint complete: fold and reset
                const int j = gs >> 2;
                const float p0a = (float)pal[col][3 * j + 0];
                const float p1a = (float)pal[col][3 * j + 1];
                const float p2a = (float)pal[col][3 * j + 2];
                #pragma unroll
                for (int r = 0; r < 4; ++r) {
                    const float d0 = xa[r0 + r][3 * j + 0] - p0a;
                    const float d1 = xa[r0 + r][3 * j + 1] - p1a;
                    const float d2 = xa[r0 + r][3 * j + 2] - p2a;
                    const float dist = sqrtf(d0 * d0 + d1 * d1 + d2 * d2);
                    const float e = __expf(dist * 0.005f);   // in [1, ~1.05]
                    den[r] += e;
                    num[r] += e * aj[r];
                }
                aj = f32x4{0.f, 0.f, 0.f, 0.f};
            }
        }
    }
    #undef ISSUE

    // ---- row norms: lanes {lr, lr+16, lr+32, lr+48} hold row-lr partials ----
    ssq += __shfl_xor(ssq, 16);
    ssq += __shfl_xor(ssq, 32);

    float rn[4];
    #pragma unroll
    for (int r = 0; r < 4; ++r)
        rn[r] = 240.f / fmaxf(sqrtf(__shfl(ssq, r0 + r)), 1e-12f);   // 16*15/norm

    if (col < NCLS) {
        #pragma unroll
        for (int r = 0; r < 4; ++r)
            out[(size_t)(m0 + r0 + r) * NCLS + col] = rn[r] * num[r] / den[r];
    }
}

extern "C" void kernel_launch(void* const* d_in, const int* in_sizes, int n_in,
                              void* d_out, int out_size, void* d_ws, size_t ws_size,
                              hipStream_t stream) {
    const float* emb = (const float*)d_in[0];
    const float* W   = (const float*)d_in[1];
    float* out = (float*)d_out;
    __bf16* pnf = (__bf16*)d_ws;
    float*  pa  = (float*)((char*)d_ws + PNF_BYTES);
    const int B = in_sizes[0] / E;           // 16384

    prep_kernel<<<NPAD, 256, 0, stream>>>(W, pnf, pa);
    cos_kernel<<<B / 16, 320, 0, stream>>>(emb, pnf, pa, out);
}